// Round 3
// baseline (1453.112 us; speedup 1.0000x reference)
//
#include <hip/hip_runtime.h>
#include <hip/hip_bf16.h>

// ---------------------------------------------------------------------------
// TransformerSquared forward on MI355X.
// R2: all GEMMs -> m97-structure (global_load_lds 16B staging, 128x128 or
// 64x64 tiles, 2-barrier K-loop) + XCD-aware block swizzle (bm-fastest).
// ---------------------------------------------------------------------------

#define T_SEQ 2048
#define DMODEL 1024
#define NHEAD 16
#define HSZ 64
#define NLAYER 4
#define FFDIM 4096
#define RH 16
#define RP 256
#define RF 256
#define VOCAB 32000
#define NKQV (3 * NHEAD * RH) // 768

typedef short short8 __attribute__((ext_vector_type(8)));
typedef float f32x4 __attribute__((ext_vector_type(4)));
typedef unsigned int uint_t;
typedef unsigned short ushort_t;

__device__ __forceinline__ float bfbits2f(uint_t bits16_in_low) {
    uint_t b = bits16_in_low << 16;
    float f;
    __builtin_memcpy(&f, &b, 4);
    return f;
}
__device__ __forceinline__ ushort_t f2bfu(float f) {
    union { __hip_bfloat16 b; ushort_t u; } cv;
    cv.b = __float2bfloat16(f);
    return cv.u;
}

// async global->LDS, 16 bytes per lane. LDS dest = wave-uniform base + lane*16.
__device__ __forceinline__ void gld16(const __hip_bfloat16* g, short* l) {
    __builtin_amdgcn_global_load_lds(
        (const __attribute__((address_space(1))) void*)g,
        (__attribute__((address_space(3))) void*)l, 16, 0, 0);
}

// ------------------------------- f32 -> bf16 -------------------------------
__global__ __launch_bounds__(256) void cvt_k(const float* __restrict__ in,
                                             __hip_bfloat16* __restrict__ out, int n4) {
    int i = blockIdx.x * 256 + threadIdx.x;
    if (i >= n4) return;
    float4 v = ((const float4*)in)[i];
    ushort4 o;
    o.x = f2bfu(v.x); o.y = f2bfu(v.y); o.z = f2bfu(v.z); o.w = f2bfu(v.w);
    ((ushort4*)out)[i] = o;
}

// ------------------------------- embedding ---------------------------------
__global__ __launch_bounds__(256) void embed_k(const int* __restrict__ idx,
                                               const float* __restrict__ tok,
                                               const float* __restrict__ pos,
                                               float* __restrict__ x) {
    int i = blockIdx.x * 256 + threadIdx.x;          // over T*D/4
    int d4 = i & (DMODEL / 4 - 1);
    int t = i >> 8;                                   // D/4 = 256
    int tk = idx[t];
    float4 a = ((const float4*)(tok + (size_t)tk * DMODEL))[d4];
    float4 p = ((const float4*)(pos + (size_t)t * DMODEL))[d4];
    a.x += p.x; a.y += p.y; a.z += p.z; a.w += p.w;
    ((float4*)(x + (size_t)t * DMODEL))[d4] = a;
}

// ------------------------------- layernorm ---------------------------------
__global__ __launch_bounds__(256) void ln_k(const float* __restrict__ xin,
                                            const float* __restrict__ w,
                                            const float* __restrict__ b,
                                            __hip_bfloat16* __restrict__ out) {
    const int row = blockIdx.x, tid = threadIdx.x;
    const float4 v = ((const float4*)(xin + (size_t)row * DMODEL))[tid];
    float s = v.x + v.y + v.z + v.w;
    float q = v.x * v.x + v.y * v.y + v.z * v.z + v.w * v.w;
    for (int off = 32; off; off >>= 1) { s += __shfl_xor(s, off); q += __shfl_xor(q, off); }
    __shared__ float rs_[4], rq_[4];
    if ((tid & 63) == 0) { rs_[tid >> 6] = s; rq_[tid >> 6] = q; }
    __syncthreads();
    s = rs_[0] + rs_[1] + rs_[2] + rs_[3];
    q = rq_[0] + rq_[1] + rq_[2] + rq_[3];
    const float mean = s * (1.f / DMODEL);
    const float var = q * (1.f / DMODEL) - mean * mean;
    const float rstd = rsqrtf(var + 1e-5f);
    const float4 wv = ((const float4*)w)[tid];
    const float4 bv = ((const float4*)b)[tid];
    ushort4 o;
    o.x = f2bfu((v.x - mean) * rstd * wv.x + bv.x);
    o.y = f2bfu((v.y - mean) * rstd * wv.y + bv.y);
    o.z = f2bfu((v.z - mean) * rstd * wv.z + bv.z);
    o.w = f2bfu((v.w - mean) * rstd * wv.w + bv.w);
    ((ushort4*)out)[(size_t)row * (DMODEL / 4) + tid] = o;
}

// --------------------------- generic GEMM (A * B^T) ------------------------
// A: [M,K] bf16 row-major.  B: [N,K] bf16 row-major.  BK = 64 fixed.
// 256 threads = 4 waves. BN>=128: 2x2 waves of 64x64. BN==64: 4x1 waves.
// MODE 0: Cb = bf16(acc * colscale[col]);  1: Cb = bf16(gelu(acc));
// MODE 2: Cf += acc;  3: Cf = acc.
template <int BM, int BN, int MODE>
__global__ __launch_bounds__(256) void gemm_t(const __hip_bfloat16* __restrict__ A,
                                              const __hip_bfloat16* __restrict__ B,
                                              const float* __restrict__ colscale,
                                              __hip_bfloat16* __restrict__ Cb,
                                              float* __restrict__ Cf,
                                              int M, int N, int K) {
    constexpr int WM = (BN >= 128) ? 2 : 4;
    constexpr int WN = 4 / WM;
    constexpr int TM = BM / WM / 16;
    constexpr int TN = BN / WN / 16;
    constexpr int IA = BM / 32;     // gld16 iters for A tile
    constexpr int IB = BN / 32;
    __shared__ short As[BM * 64];
    __shared__ short Bs[BN * 64];
    const int tid = threadIdx.x;
    const int w = tid >> 6, ln = tid & 63, lr = ln & 15, lg = ln >> 4;
    const int GM = M / BM;

    // XCD-aware swizzle (all our grids are divisible by 8), bm-fastest.
    const int nwg = gridDim.x;
    const int cpx = nwg >> 3;
    const int wg = (blockIdx.x & 7) * cpx + (blockIdx.x >> 3);
    const int bm = wg % GM, bn = wg / GM;
    const int wm = w / WN, wn = w % WN;

    f32x4 acc[TM][TN] = {};

    const int srow = tid >> 3, scol = (tid & 7) * 8;
    const __hip_bfloat16* Ag = A + (size_t)(bm * BM + srow) * K + scol;
    const __hip_bfloat16* Bg = B + (size_t)(bn * BN + srow) * K + scol;

    for (int kt = 0; kt < K; kt += 64) {
        __syncthreads();   // previous tile consumed
#pragma unroll
        for (int i = 0; i < IA; ++i)
            gld16(Ag + (size_t)(i * 32) * K + kt, &As[i * 2048 + w * 512]);
#pragma unroll
        for (int i = 0; i < IB; ++i)
            gld16(Bg + (size_t)(i * 32) * K + kt, &Bs[i * 2048 + w * 512]);
        __syncthreads();   // drains vmcnt + barrier

#pragma unroll
        for (int kk = 0; kk < 2; ++kk) {
            short8 af[TM], bf[TN];
#pragma unroll
            for (int m = 0; m < TM; ++m)
                af[m] = *(const short8*)&As[(wm * (BM / WM) + m * 16 + lr) * 64 + kk * 32 + lg * 8];
#pragma unroll
            for (int n = 0; n < TN; ++n)
                bf[n] = *(const short8*)&Bs[(wn * (BN / WN) + n * 16 + lr) * 64 + kk * 32 + lg * 8];
#pragma unroll
            for (int m = 0; m < TM; ++m)
#pragma unroll
                for (int n = 0; n < TN; ++n)
                    acc[m][n] = __builtin_amdgcn_mfma_f32_16x16x32_bf16(af[m], bf[n], acc[m][n], 0, 0, 0);
        }
    }

#pragma unroll
    for (int n = 0; n < TN; ++n) {
        const int col = bn * BN + wn * (BN / WN) + n * 16 + lr;
        float cs = 1.0f;
        if (MODE == 0 && colscale) cs = colscale[col];
#pragma unroll
        for (int m = 0; m < TM; ++m) {
#pragma unroll
            for (int rr = 0; rr < 4; ++rr) {
                const int row = bm * BM + wm * (BM / WM) + m * 16 + lg * 4 + rr;
                float v = acc[m][n][rr];
                const size_t o = (size_t)row * N + col;
                if (MODE == 0) {
                    Cb[o] = __float2bfloat16(v * cs);
                } else if (MODE == 1) {
                    v = 0.5f * v * (1.0f + erff(v * 0.70710678118654752f));
                    Cb[o] = __float2bfloat16(v);
                } else if (MODE == 2) {
                    Cf[o] += v;
                } else {
                    Cf[o] = v;
                }
            }
        }
    }
}

// ----------------------- per-head SVF U-projection (K=16) ------------------
__global__ __launch_bounds__(256) void kqv2_k(const __hip_bfloat16* __restrict__ t1,
                                              const __hip_bfloat16* __restrict__ U,
                                              __hip_bfloat16* __restrict__ kqv) {
    size_t i = (size_t)blockIdx.x * 256 + threadIdx.x; // 3*16*2048*64
    int s = (int)(i & 63);
    size_t rest = i >> 6;
    int t = (int)(rest & (T_SEQ - 1));
    int gh = (int)(rest >> 11);
    const short8* trow = (const short8*)(t1 + (size_t)t * NKQV + gh * RH);
    const short8* urow = (const short8*)(U + ((size_t)gh * HSZ + s) * RH);
    short8 ta = trow[0], tb = trow[1];
    short8 ua = urow[0], ub = urow[1];
    float acc = 0.f;
#pragma unroll
    for (int j = 0; j < 8; ++j) {
        acc += bfbits2f((ushort_t)ta[j]) * bfbits2f((ushort_t)ua[j]);
        acc += bfbits2f((ushort_t)tb[j]) * bfbits2f((ushort_t)ub[j]);
    }
    kqv[i] = __float2bfloat16(acc);
}

// --------------------------- V transpose per head --------------------------
__global__ __launch_bounds__(256) void vtrans_k(const __hip_bfloat16* __restrict__ vb,
                                                __hip_bfloat16* __restrict__ vt) {
    __shared__ short Ts[64][72];
    const int ti = blockIdx.x, h = blockIdx.y, tid = threadIdx.x;
    const int tl = tid >> 2, sc = (tid & 3) * 16;
    const short* src = (const short*)(vb + ((size_t)h * T_SEQ + ti * 64 + tl) * HSZ + sc);
    short8 a = ((const short8*)src)[0];
    short8 b = ((const short8*)src)[1];
#pragma unroll
    for (int j = 0; j < 8; ++j) { Ts[sc + j][tl] = a[j]; Ts[sc + 8 + j][tl] = b[j]; }
    __syncthreads();
    const int s = tid >> 2;
    short8 o0, o1;
#pragma unroll
    for (int j = 0; j < 8; ++j) { o0[j] = Ts[s][sc + j]; o1[j] = Ts[s][sc + 8 + j]; }
    short* dst = (short*)(vt + ((size_t)h * HSZ + s) * T_SEQ + ti * 64 + sc);
    ((short8*)dst)[0] = o0;
    ((short8*)dst)[1] = o1;
}

// --------------------------- MFMA flash attention --------------------------
__global__ __launch_bounds__(256) void attn_k(const __hip_bfloat16* __restrict__ qb,
                                              const __hip_bfloat16* __restrict__ kb,
                                              const __hip_bfloat16* __restrict__ vtb,
                                              __hip_bfloat16* __restrict__ attout) {
    __shared__ short P_s[2][4][16 * 40];  // [dbuf][wave][16 q x 32 u], stride 40
    const int tid = threadIdx.x, w = tid >> 6, ln = tid & 63;
    const int lr = ln & 15, lg = ln >> 4;
    const int h = blockIdx.y;
    const int t0 = blockIdx.x * 16 + w * 512;
    const size_t hb = (size_t)h * T_SEQ;
    const size_t vtbase = (size_t)h * HSZ * T_SEQ;

    short8 qf0 = *(const short8*)(qb + (hb + t0 + lr) * HSZ + lg * 8);
    short8 qf1 = *(const short8*)(qb + (hb + t0 + lr) * HSZ + 32 + lg * 8);

    f32x4 acc[4] = {};
    float mrun = -3e38f, lrun = 0.f;
    int pbuf = 0;

    short8 kf0 = *(const short8*)(kb + (hb + 0 + lr) * HSZ + lg * 8);
    short8 kf1 = *(const short8*)(kb + (hb + 0 + lr) * HSZ + 32 + lg * 8);
    short8 kf2 = *(const short8*)(kb + (hb + 16 + lr) * HSZ + lg * 8);
    short8 kf3 = *(const short8*)(kb + (hb + 16 + lr) * HSZ + 32 + lg * 8);

    for (int u0 = 0; u0 <= t0 + 15; u0 += 32) {
        f32x4 st0 = {}, st1 = {};
        st0 = __builtin_amdgcn_mfma_f32_16x16x32_bf16(kf0, qf0, st0, 0, 0, 0);
        st0 = __builtin_amdgcn_mfma_f32_16x16x32_bf16(kf1, qf1, st0, 0, 0, 0);
        st1 = __builtin_amdgcn_mfma_f32_16x16x32_bf16(kf2, qf0, st1, 0, 0, 0);
        st1 = __builtin_amdgcn_mfma_f32_16x16x32_bf16(kf3, qf1, st1, 0, 0, 0);

        const int un = u0 + 32;
        if (un <= t0 + 15) {
            kf0 = *(const short8*)(kb + (hb + un + lr) * HSZ + lg * 8);
            kf1 = *(const short8*)(kb + (hb + un + lr) * HSZ + 32 + lg * 8);
            kf2 = *(const short8*)(kb + (hb + un + 16 + lr) * HSZ + lg * 8);
            kf3 = *(const short8*)(kb + (hb + un + 16 + lr) * HSZ + 32 + lg * 8);
        }
        short8 vf0 = *(const short8*)(vtb + vtbase + (size_t)(0 * 16 + lr) * T_SEQ + u0 + lg * 8);
        short8 vf1 = *(const short8*)(vtb + vtbase + (size_t)(1 * 16 + lr) * T_SEQ + u0 + lg * 8);
        short8 vf2 = *(const short8*)(vtb + vtbase + (size_t)(2 * 16 + lr) * T_SEQ + u0 + lg * 8);
        short8 vf3 = *(const short8*)(vtb + vtbase + (size_t)(3 * 16 + lr) * T_SEQ + u0 + lg * 8);

        const int qg = t0 + lr;
        const bool needm0 = (u0 + 15 > t0);
        const bool needm1 = (u0 + 31 > t0);
        float sv[8];
#pragma unroll
        for (int r = 0; r < 4; ++r) {
            float v0 = st0[r] * 0.125f;
            if (needm0 && (u0 + lg * 4 + r > qg)) v0 = -1e30f;
            sv[r] = v0;
            float v1 = st1[r] * 0.125f;
            if (needm1 && (u0 + 16 + lg * 4 + r > qg)) v1 = -1e30f;
            sv[4 + r] = v1;
        }
        float tm = sv[0];
#pragma unroll
        for (int j = 1; j < 8; ++j) tm = fmaxf(tm, sv[j]);
        tm = fmaxf(tm, __shfl_xor(tm, 16));
        tm = fmaxf(tm, __shfl_xor(tm, 32));
        const float mnew = fmaxf(mrun, tm);
        const float corr = __expf(mrun - mnew);
        float pv[8];
        float ls = 0.f;
#pragma unroll
        for (int j = 0; j < 8; ++j) { pv[j] = __expf(sv[j] - mnew); ls += pv[j]; }
        ls += __shfl_xor(ls, 16);
        ls += __shfl_xor(ls, 32);
        lrun = lrun * corr + ls;
#pragma unroll
        for (int dt = 0; dt < 4; ++dt) acc[dt] *= corr;

        uint_t* pw = (uint_t*)P_s[pbuf][w];
        const int wb = lr * 20 + lg * 2;
        pw[wb + 0] = (uint_t)f2bfu(pv[0]) | ((uint_t)f2bfu(pv[1]) << 16);
        pw[wb + 1] = (uint_t)f2bfu(pv[2]) | ((uint_t)f2bfu(pv[3]) << 16);
        pw[wb + 8] = (uint_t)f2bfu(pv[4]) | ((uint_t)f2bfu(pv[5]) << 16);
        pw[wb + 9] = (uint_t)f2bfu(pv[6]) | ((uint_t)f2bfu(pv[7]) << 16);
        asm volatile("s_waitcnt lgkmcnt(0)" ::: "memory");
        short8 pf = *(const short8*)(&P_s[pbuf][w][lr * 40 + lg * 8]);

        acc[0] = __builtin_amdgcn_mfma_f32_16x16x32_bf16(vf0, pf, acc[0], 0, 0, 0);
        acc[1] = __builtin_amdgcn_mfma_f32_16x16x32_bf16(vf1, pf, acc[1], 0, 0, 0);
        acc[2] = __builtin_amdgcn_mfma_f32_16x16x32_bf16(vf2, pf, acc[2], 0, 0, 0);
        acc[3] = __builtin_amdgcn_mfma_f32_16x16x32_bf16(vf3, pf, acc[3], 0, 0, 0);

        mrun = mnew;
        pbuf ^= 1;
    }

    const float inv = 1.f / lrun;
#pragma unroll
    for (int dt = 0; dt < 4; ++dt) {
#pragma unroll
        for (int r = 0; r < 4; r += 2) {
            uint_t pk = (uint_t)f2bfu(acc[dt][r] * inv) |
                        ((uint_t)f2bfu(acc[dt][r + 1] * inv) << 16);
            *(uint_t*)(attout + (size_t)(t0 + lr) * DMODEL + h * HSZ + dt * 16 + lg * 4 + r) = pk;
        }
    }
}

// ---------------------------------------------------------------------------
extern "C" void kernel_launch(void* const* d_in, const int* in_sizes, int n_in,
                              void* d_out, int out_size, void* d_ws, size_t ws_size,
                              hipStream_t stream) {
    const int* idx = (const int*)d_in[0];
    const float* tok_emb = (const float*)d_in[1];
    const float* pos_emb = (const float*)d_in[2];
    const float* ln1_w = (const float*)d_in[3];
    const float* ln1_b = (const float*)d_in[4];
    const float* ln2_w = (const float*)d_in[5];
    const float* ln2_b = (const float*)d_in[6];
    const float* kqv_V = (const float*)d_in[7];
    const float* kqv_z = (const float*)d_in[8];
    const float* kqv_U = (const float*)d_in[9];
    const float* proj_V = (const float*)d_in[10];
    const float* proj_z = (const float*)d_in[11];
    const float* proj_U = (const float*)d_in[12];
    const float* f1_V = (const float*)d_in[13];
    const float* f1_z = (const float*)d_in[14];
    const float* f1_U = (const float*)d_in[15];
    const float* f2_V = (const float*)d_in[16];
    const float* f2_z = (const float*)d_in[17];
    const float* f2_U = (const float*)d_in[18];
    const float* lnf_w = (const float*)d_in[19];
    const float* lnf_b = (const float*)d_in[20];
    const float* lm_w = (const float*)d_in[21];

    // ---------------- workspace layout ----------------
    char* W = (char*)d_ws;
    float* x = (float*)W;                 W += (size_t)T_SEQ * DMODEL * 4;
    __hip_bfloat16* hbuf = (__hip_bfloat16*)W; W += (size_t)T_SEQ * DMODEL * 2;
    __hip_bfloat16* t1 = (__hip_bfloat16*)W;   W += (size_t)T_SEQ * NKQV * 2;
    __hip_bfloat16* kqvb = (__hip_bfloat16*)W; W += (size_t)3 * NHEAD * T_SEQ * HSZ * 2;
    __hip_bfloat16* vtb = (__hip_bfloat16*)W;  W += (size_t)NHEAD * HSZ * T_SEQ * 2;
    __hip_bfloat16* attb = (__hip_bfloat16*)W; W += (size_t)T_SEQ * DMODEL * 2;
    __hip_bfloat16* ffb = (__hip_bfloat16*)W;  W += (size_t)T_SEQ * FFDIM * 2;
    __hip_bfloat16* wkV = (__hip_bfloat16*)W;  W += (size_t)NLAYER * NKQV * DMODEL * 2;
    __hip_bfloat16* wkU = (__hip_bfloat16*)W;  W += (size_t)NLAYER * 3 * NHEAD * HSZ * RH * 2;
    __hip_bfloat16* wpV = (__hip_bfloat16*)W;  W += (size_t)NLAYER * RP * DMODEL * 2;
    __hip_bfloat16* wpU = (__hip_bfloat16*)W;  W += (size_t)NLAYER * DMODEL * RP * 2;
    __hip_bfloat16* w1V = (__hip_bfloat16*)W;  W += (size_t)NLAYER * RF * DMODEL * 2;
    __hip_bfloat16* w1U = (__hip_bfloat16*)W;  W += (size_t)NLAYER * FFDIM * RF * 2;
    __hip_bfloat16* w2V = (__hip_bfloat16*)W;  W += (size_t)NLAYER * RF * FFDIM * 2;
    __hip_bfloat16* w2U = (__hip_bfloat16*)W;  W += (size_t)NLAYER * DMODEL * RF * 2;
    __hip_bfloat16* wlm = (__hip_bfloat16*)W;  W += (size_t)VOCAB * DMODEL * 2;

    auto cvt = [&](const float* src, __hip_bfloat16* dst, size_t n) {
        int n4 = (int)(n / 4);
        cvt_k<<<dim3((n4 + 255) / 256), dim3(256), 0, stream>>>(src, dst, n4);
    };
    cvt(kqv_V, wkV, (size_t)NLAYER * NKQV * DMODEL);
    cvt(kqv_U, wkU, (size_t)NLAYER * 3 * NHEAD * HSZ * RH);
    cvt(proj_V, wpV, (size_t)NLAYER * RP * DMODEL);
    cvt(proj_U, wpU, (size_t)NLAYER * DMODEL * RP);
    cvt(f1_V, w1V, (size_t)NLAYER * RF * DMODEL);
    cvt(f1_U, w1U, (size_t)NLAYER * FFDIM * RF);
    cvt(f2_V, w2V, (size_t)NLAYER * RF * FFDIM);
    cvt(f2_U, w2U, (size_t)NLAYER * DMODEL * RF);
    cvt(lm_w, wlm, (size_t)VOCAB * DMODEL);

    embed_k<<<dim3(T_SEQ * DMODEL / 4 / 256), dim3(256), 0, stream>>>(idx, tok_emb, pos_emb, x);

    const int M = T_SEQ;
    for (int l = 0; l < NLAYER; ++l) {
        ln_k<<<dim3(T_SEQ), dim3(256), 0, stream>>>(x, ln1_w + l * DMODEL, ln1_b + l * DMODEL, hbuf);
        // kqv V-projection + z scale: [T,768]  (N=768 -> 64x64 tiles)
        gemm_t<64, 64, 0><<<dim3((M / 64) * (NKQV / 64)), dim3(256), 0, stream>>>(
            hbuf, wkV + (size_t)l * NKQV * DMODEL, kqv_z + (size_t)l * NKQV,
            t1, nullptr, M, NKQV, DMODEL);
        kqv2_k<<<dim3(3 * NHEAD * T_SEQ * HSZ / 256), dim3(256), 0, stream>>>(
            t1, wkU + (size_t)l * 3 * NHEAD * HSZ * RH, kqvb);
        {
            const __hip_bfloat16* kk = kqvb;
            const __hip_bfloat16* qq = kqvb + (size_t)NHEAD * T_SEQ * HSZ;
            const __hip_bfloat16* vv = kqvb + (size_t)2 * NHEAD * T_SEQ * HSZ;
            vtrans_k<<<dim3(T_SEQ / 64, NHEAD), dim3(256), 0, stream>>>(vv, vtb);
            attn_k<<<dim3(T_SEQ / 64, NHEAD), dim3(256), 0, stream>>>(qq, kk, vtb, attb);
        }
        // proj SVF
        gemm_t<64, 64, 0><<<dim3((M / 64) * (RP / 64)), dim3(256), 0, stream>>>(
            attb, wpV + (size_t)l * RP * DMODEL, proj_z + (size_t)l * RP,
            t1, nullptr, M, RP, DMODEL);
        gemm_t<128, 128, 2><<<dim3((M / 128) * (DMODEL / 128)), dim3(256), 0, stream>>>(
            t1, wpU + (size_t)l * DMODEL * RP, nullptr,
            nullptr, x, M, DMODEL, RP);
        ln_k<<<dim3(T_SEQ), dim3(256), 0, stream>>>(x, ln2_w + l * DMODEL, ln2_b + l * DMODEL, hbuf);
        // ffn
        gemm_t<64, 64, 0><<<dim3((M / 64) * (RF / 64)), dim3(256), 0, stream>>>(
            hbuf, w1V + (size_t)l * RF * DMODEL, f1_z + (size_t)l * RF,
            t1, nullptr, M, RF, DMODEL);
        gemm_t<128, 128, 1><<<dim3((M / 128) * (FFDIM / 128)), dim3(256), 0, stream>>>(
            t1, w1U + (size_t)l * FFDIM * RF, nullptr,
            ffb, nullptr, M, FFDIM, RF);
        gemm_t<64, 64, 0><<<dim3((M / 64) * (RF / 64)), dim3(256), 0, stream>>>(
            ffb, w2V + (size_t)l * RF * FFDIM, f2_z + (size_t)l * RF,
            t1, nullptr, M, RF, FFDIM);
        gemm_t<128, 128, 2><<<dim3((M / 128) * (DMODEL / 128)), dim3(256), 0, stream>>>(
            t1, w2U + (size_t)l * DMODEL * RF, nullptr,
            nullptr, x, M, DMODEL, RF);
    }
    ln_k<<<dim3(T_SEQ), dim3(256), 0, stream>>>(x, lnf_w, lnf_b, hbuf);
    gemm_t<128, 128, 3><<<dim3((M / 128) * (VOCAB / 128)), dim3(256), 0, stream>>>(
        hbuf, wlm, nullptr, nullptr, (float*)d_out, M, VOCAB, DMODEL);
}

// Round 4
// 1336.472 us; speedup vs baseline: 1.0873x; 1.0873x over previous
//
#include <hip/hip_runtime.h>
#include <hip/hip_bf16.h>

// ---------------------------------------------------------------------------
// TransformerSquared forward on MI355X.
// R3: gemm_t gets both-sides LDS XOR swizzle (pre-swizzled global source for
// global_load_lds + swizzled ds_read) killing the 4.9e7 bank conflicts.
// attn_k: KVBLK=64 (4 indep QK chains, 8 PV mfma per softmax round).
// ---------------------------------------------------------------------------

#define T_SEQ 2048
#define DMODEL 1024
#define NHEAD 16
#define HSZ 64
#define NLAYER 4
#define FFDIM 4096
#define RH 16
#define RP 256
#define RF 256
#define VOCAB 32000
#define NKQV (3 * NHEAD * RH) // 768

typedef short short8 __attribute__((ext_vector_type(8)));
typedef float f32x4 __attribute__((ext_vector_type(4)));
typedef unsigned int uint_t;
typedef unsigned short ushort_t;

__device__ __forceinline__ float bfbits2f(uint_t bits16_in_low) {
    uint_t b = bits16_in_low << 16;
    float f;
    __builtin_memcpy(&f, &b, 4);
    return f;
}
__device__ __forceinline__ ushort_t f2bfu(float f) {
    union { __hip_bfloat16 b; ushort_t u; } cv;
    cv.b = __float2bfloat16(f);
    return cv.u;
}
__device__ __forceinline__ uint_t pack2bf(float a, float b) {
    return (uint_t)f2bfu(a) | ((uint_t)f2bfu(b) << 16);
}

// async global->LDS, 16 bytes per lane. LDS dest = wave-uniform base + lane*16.
__device__ __forceinline__ void gld16(const __hip_bfloat16* g, short* l) {
    __builtin_amdgcn_global_load_lds(
        (const __attribute__((address_space(1))) void*)g,
        (__attribute__((address_space(3))) void*)l, 16, 0, 0);
}

// ------------------------------- f32 -> bf16 -------------------------------
__global__ __launch_bounds__(256) void cvt_k(const float* __restrict__ in,
                                             __hip_bfloat16* __restrict__ out, int n4) {
    int i = blockIdx.x * 256 + threadIdx.x;
    if (i >= n4) return;
    float4 v = ((const float4*)in)[i];
    ushort4 o;
    o.x = f2bfu(v.x); o.y = f2bfu(v.y); o.z = f2bfu(v.z); o.w = f2bfu(v.w);
    ((ushort4*)out)[i] = o;
}

// ------------------------------- embedding ---------------------------------
__global__ __launch_bounds__(256) void embed_k(const int* __restrict__ idx,
                                               const float* __restrict__ tok,
                                               const float* __restrict__ pos,
                                               float* __restrict__ x) {
    int i = blockIdx.x * 256 + threadIdx.x;          // over T*D/4
    int d4 = i & (DMODEL / 4 - 1);
    int t = i >> 8;                                   // D/4 = 256
    int tk = idx[t];
    float4 a = ((const float4*)(tok + (size_t)tk * DMODEL))[d4];
    float4 p = ((const float4*)(pos + (size_t)t * DMODEL))[d4];
    a.x += p.x; a.y += p.y; a.z += p.z; a.w += p.w;
    ((float4*)(x + (size_t)t * DMODEL))[d4] = a;
}

// ------------------------------- layernorm ---------------------------------
__global__ __launch_bounds__(256) void ln_k(const float* __restrict__ xin,
                                            const float* __restrict__ w,
                                            const float* __restrict__ b,
                                            __hip_bfloat16* __restrict__ out) {
    const int row = blockIdx.x, tid = threadIdx.x;
    const float4 v = ((const float4*)(xin + (size_t)row * DMODEL))[tid];
    float s = v.x + v.y + v.z + v.w;
    float q = v.x * v.x + v.y * v.y + v.z * v.z + v.w * v.w;
    for (int off = 32; off; off >>= 1) { s += __shfl_xor(s, off); q += __shfl_xor(q, off); }
    __shared__ float rs_[4], rq_[4];
    if ((tid & 63) == 0) { rs_[tid >> 6] = s; rq_[tid >> 6] = q; }
    __syncthreads();
    s = rs_[0] + rs_[1] + rs_[2] + rs_[3];
    q = rq_[0] + rq_[1] + rq_[2] + rq_[3];
    const float mean = s * (1.f / DMODEL);
    const float var = q * (1.f / DMODEL) - mean * mean;
    const float rstd = rsqrtf(var + 1e-5f);
    const float4 wv = ((const float4*)w)[tid];
    const float4 bv = ((const float4*)b)[tid];
    ushort4 o;
    o.x = f2bfu((v.x - mean) * rstd * wv.x + bv.x);
    o.y = f2bfu((v.y - mean) * rstd * wv.y + bv.y);
    o.z = f2bfu((v.z - mean) * rstd * wv.z + bv.z);
    o.w = f2bfu((v.w - mean) * rstd * wv.w + bv.w);
    ((ushort4*)out)[(size_t)row * (DMODEL / 4) + tid] = o;
}

// --------------------------- generic GEMM (A * B^T) ------------------------
// A: [M,K] bf16 row-major.  B: [N,K] bf16 row-major.  BK = 64 fixed.
// LDS layout: row-major [row][64] with 16B-unit XOR swizzle:
//   data for global unit u (0..7) of row r stored at unit u ^ (r&7).
//   gld16 writes linearly -> global source col is pre-swizzled per lane.
template <int BM, int BN, int MODE>
__global__ __launch_bounds__(256) void gemm_t(const __hip_bfloat16* __restrict__ A,
                                              const __hip_bfloat16* __restrict__ B,
                                              const float* __restrict__ colscale,
                                              __hip_bfloat16* __restrict__ Cb,
                                              float* __restrict__ Cf,
                                              int M, int N, int K) {
    constexpr int WM = (BN >= 128) ? 2 : 4;
    constexpr int WN = 4 / WM;
    constexpr int TM = BM / WM / 16;
    constexpr int TN = BN / WN / 16;
    constexpr int IA = BM / 32;     // gld16 iters for A tile
    constexpr int IB = BN / 32;
    __shared__ short As[BM * 64];
    __shared__ short Bs[BN * 64];
    const int tid = threadIdx.x;
    const int w = tid >> 6, ln = tid & 63, lr = ln & 15, lg = ln >> 4;
    const int GM = M / BM;

    // XCD-aware swizzle (all our grids are divisible by 8), bm-fastest.
    const int nwg = gridDim.x;
    const int cpx = nwg >> 3;
    const int wg = (blockIdx.x & 7) * cpx + (blockIdx.x >> 3);
    const int bm = wg % GM, bn = wg / GM;
    const int wm = w / WN, wn = w % WN;

    f32x4 acc[TM][TN] = {};

    const int srow = tid >> 3;
    // pre-swizzled source column: lane (writing LDS unit ln&7 of row with
    // row&7 == (tid>>3)&7) fetches global unit (ln&7) ^ (row&7).
    const int scol = (((tid & 7) ^ ((tid >> 3) & 7)) * 8);
    const __hip_bfloat16* Ag = A + (size_t)(bm * BM + srow) * K + scol;
    const __hip_bfloat16* Bg = B + (size_t)(bn * BN + srow) * K + scol;

    for (int kt = 0; kt < K; kt += 64) {
        __syncthreads();   // previous tile consumed
#pragma unroll
        for (int i = 0; i < IA; ++i)
            gld16(Ag + (size_t)(i * 32) * K + kt, &As[i * 2048 + w * 512]);
#pragma unroll
        for (int i = 0; i < IB; ++i)
            gld16(Bg + (size_t)(i * 32) * K + kt, &Bs[i * 2048 + w * 512]);
        __syncthreads();   // drains vmcnt + barrier

#pragma unroll
        for (int kk = 0; kk < 2; ++kk) {
            short8 af[TM], bf[TN];
#pragma unroll
            for (int m = 0; m < TM; ++m) {
                const int row = wm * (BM / WM) + m * 16 + lr;
                af[m] = *(const short8*)&As[row * 64 + (((kk * 4 + lg) ^ (lr & 7)) * 8)];
            }
#pragma unroll
            for (int n = 0; n < TN; ++n) {
                const int row = wn * (BN / WN) + n * 16 + lr;
                bf[n] = *(const short8*)&Bs[row * 64 + (((kk * 4 + lg) ^ (lr & 7)) * 8)];
            }
#pragma unroll
            for (int m = 0; m < TM; ++m)
#pragma unroll
                for (int n = 0; n < TN; ++n)
                    acc[m][n] = __builtin_amdgcn_mfma_f32_16x16x32_bf16(af[m], bf[n], acc[m][n], 0, 0, 0);
        }
    }

#pragma unroll
    for (int n = 0; n < TN; ++n) {
        const int col = bn * BN + wn * (BN / WN) + n * 16 + lr;
        float cs = 1.0f;
        if (MODE == 0 && colscale) cs = colscale[col];
#pragma unroll
        for (int m = 0; m < TM; ++m) {
#pragma unroll
            for (int rr = 0; rr < 4; ++rr) {
                const int row = bm * BM + wm * (BM / WM) + m * 16 + lg * 4 + rr;
                float v = acc[m][n][rr];
                const size_t o = (size_t)row * N + col;
                if (MODE == 0) {
                    Cb[o] = __float2bfloat16(v * cs);
                } else if (MODE == 1) {
                    v = 0.5f * v * (1.0f + erff(v * 0.70710678118654752f));
                    Cb[o] = __float2bfloat16(v);
                } else if (MODE == 2) {
                    Cf[o] += v;
                } else {
                    Cf[o] = v;
                }
            }
        }
    }
}

// ----------------------- per-head SVF U-projection (K=16) ------------------
__global__ __launch_bounds__(256) void kqv2_k(const __hip_bfloat16* __restrict__ t1,
                                              const __hip_bfloat16* __restrict__ U,
                                              __hip_bfloat16* __restrict__ kqv) {
    size_t i = (size_t)blockIdx.x * 256 + threadIdx.x; // 3*16*2048*64
    int s = (int)(i & 63);
    size_t rest = i >> 6;
    int t = (int)(rest & (T_SEQ - 1));
    int gh = (int)(rest >> 11);
    const short8* trow = (const short8*)(t1 + (size_t)t * NKQV + gh * RH);
    const short8* urow = (const short8*)(U + ((size_t)gh * HSZ + s) * RH);
    short8 ta = trow[0], tb = trow[1];
    short8 ua = urow[0], ub = urow[1];
    float acc = 0.f;
#pragma unroll
    for (int j = 0; j < 8; ++j) {
        acc += bfbits2f((ushort_t)ta[j]) * bfbits2f((ushort_t)ua[j]);
        acc += bfbits2f((ushort_t)tb[j]) * bfbits2f((ushort_t)ub[j]);
    }
    kqv[i] = __float2bfloat16(acc);
}

// --------------------------- V transpose per head --------------------------
__global__ __launch_bounds__(256) void vtrans_k(const __hip_bfloat16* __restrict__ vb,
                                                __hip_bfloat16* __restrict__ vt) {
    __shared__ short Ts[64][72];
    const int ti = blockIdx.x, h = blockIdx.y, tid = threadIdx.x;
    const int tl = tid >> 2, sc = (tid & 3) * 16;
    const short* src = (const short*)(vb + ((size_t)h * T_SEQ + ti * 64 + tl) * HSZ + sc);
    short8 a = ((const short8*)src)[0];
    short8 b = ((const short8*)src)[1];
#pragma unroll
    for (int j = 0; j < 8; ++j) { Ts[sc + j][tl] = a[j]; Ts[sc + 8 + j][tl] = b[j]; }
    __syncthreads();
    const int s = tid >> 2;
    short8 o0, o1;
#pragma unroll
    for (int j = 0; j < 8; ++j) { o0[j] = Ts[s][sc + j]; o1[j] = Ts[s][sc + 8 + j]; }
    short* dst = (short*)(vt + ((size_t)h * HSZ + s) * T_SEQ + ti * 64 + sc);
    ((short8*)dst)[0] = o0;
    ((short8*)dst)[1] = o1;
}

// --------------------------- MFMA flash attention --------------------------
// 1 wave = 16 q rows, KVBLK = 64 keys/iter (4 indep QK chains, 8 PV mfma).
// Block = 4 waves, strided q tiles: t0 = bi*16 + w*512.
__global__ __launch_bounds__(256) void attn_k(const __hip_bfloat16* __restrict__ qb,
                                              const __hip_bfloat16* __restrict__ kb,
                                              const __hip_bfloat16* __restrict__ vtb,
                                              __hip_bfloat16* __restrict__ attout) {
    __shared__ short P_s[2][4][16 * 72];  // [dbuf][wave][16 q x 64 u], stride 72
    const int tid = threadIdx.x, w = tid >> 6, ln = tid & 63;
    const int lr = ln & 15, lg = ln >> 4;
    const int h = blockIdx.y;
    const int t0 = blockIdx.x * 16 + w * 512;
    const size_t hb = (size_t)h * T_SEQ;
    const size_t vtbase = (size_t)h * HSZ * T_SEQ;

    short8 qf0 = *(const short8*)(qb + (hb + t0 + lr) * HSZ + lg * 8);
    short8 qf1 = *(const short8*)(qb + (hb + t0 + lr) * HSZ + 32 + lg * 8);

    f32x4 acc[4] = {};
    float mrun = -3e38f, lrun = 0.f;
    int pbuf = 0;

    short8 kf[4][2];
#pragma unroll
    for (int g = 0; g < 4; ++g) {
        kf[g][0] = *(const short8*)(kb + (hb + g * 16 + lr) * HSZ + lg * 8);
        kf[g][1] = *(const short8*)(kb + (hb + g * 16 + lr) * HSZ + 32 + lg * 8);
    }

    for (int u0 = 0; u0 <= t0 + 15; u0 += 64) {
        f32x4 st[4];
#pragma unroll
        for (int g = 0; g < 4; ++g) {
            f32x4 z = {};
            z = __builtin_amdgcn_mfma_f32_16x16x32_bf16(kf[g][0], qf0, z, 0, 0, 0);
            st[g] = __builtin_amdgcn_mfma_f32_16x16x32_bf16(kf[g][1], qf1, z, 0, 0, 0);
        }

        // prefetch next K tile (wave-uniform branch)
        const int un = u0 + 64;
        if (un <= t0 + 15) {
#pragma unroll
            for (int g = 0; g < 4; ++g) {
                kf[g][0] = *(const short8*)(kb + (hb + un + g * 16 + lr) * HSZ + lg * 8);
                kf[g][1] = *(const short8*)(kb + (hb + un + g * 16 + lr) * HSZ + 32 + lg * 8);
            }
        }
        // V tile (A operand of PV): row=d=dt*16+lr, k=u
        short8 vf[4][2];
#pragma unroll
        for (int dt = 0; dt < 4; ++dt) {
            vf[dt][0] = *(const short8*)(vtb + vtbase + (size_t)(dt * 16 + lr) * T_SEQ + u0 + lg * 8);
            vf[dt][1] = *(const short8*)(vtb + vtbase + (size_t)(dt * 16 + lr) * T_SEQ + u0 + 32 + lg * 8);
        }

        // online softmax; lane holds q = t0+lr, keys u0 + g*16 + lg*4 + r
        const int qg = t0 + lr;
        float sv[16];
#pragma unroll
        for (int g = 0; g < 4; ++g) {
            const bool needm = (u0 + g * 16 + 15 > t0);
#pragma unroll
            for (int r = 0; r < 4; ++r) {
                float v = st[g][r] * 0.125f;
                if (needm && (u0 + g * 16 + lg * 4 + r > qg)) v = -1e30f;
                sv[g * 4 + r] = v;
            }
        }
        float tm = sv[0];
#pragma unroll
        for (int j = 1; j < 16; ++j) tm = fmaxf(tm, sv[j]);
        tm = fmaxf(tm, __shfl_xor(tm, 16));
        tm = fmaxf(tm, __shfl_xor(tm, 32));
        const float mnew = fmaxf(mrun, tm);
        const float corr = __expf(mrun - mnew);
        float pv[16];
        float ls = 0.f;
#pragma unroll
        for (int j = 0; j < 16; ++j) { pv[j] = __expf(sv[j] - mnew); ls += pv[j]; }
        ls += __shfl_xor(ls, 16);
        ls += __shfl_xor(ls, 32);
        lrun = lrun * corr + ls;
#pragma unroll
        for (int dt = 0; dt < 4; ++dt) acc[dt] *= corr;

        // store P (bf16) to wave-private LDS: row q=lr (stride 72 shorts),
        // dword index within row = u/2 = g*8 + lg*2 + r/2
        uint_t* pw = (uint_t*)P_s[pbuf][w];
        const int wb = lr * 36 + lg * 2;
#pragma unroll
        for (int g = 0; g < 4; ++g) {
            pw[wb + g * 8 + 0] = pack2bf(pv[g * 4 + 0], pv[g * 4 + 1]);
            pw[wb + g * 8 + 1] = pack2bf(pv[g * 4 + 2], pv[g * 4 + 3]);
        }
        asm volatile("s_waitcnt lgkmcnt(0)" ::: "memory");
        // P fragments (B operand): col=q=lr, k=u: pf0 u=lg*8+j, pf1 u=32+lg*8+j
        short8 pf0 = *(const short8*)(&P_s[pbuf][w][lr * 72 + lg * 8]);
        short8 pf1 = *(const short8*)(&P_s[pbuf][w][lr * 72 + 32 + lg * 8]);

#pragma unroll
        for (int dt = 0; dt < 4; ++dt) {
            acc[dt] = __builtin_amdgcn_mfma_f32_16x16x32_bf16(vf[dt][0], pf0, acc[dt], 0, 0, 0);
            acc[dt] = __builtin_amdgcn_mfma_f32_16x16x32_bf16(vf[dt][1], pf1, acc[dt], 0, 0, 0);
        }

        mrun = mnew;
        pbuf ^= 1;
    }

    // out: lane holds O^T[d][q]: q=lr, d=dt*16+lg*4+r
    const float inv = 1.f / lrun;
#pragma unroll
    for (int dt = 0; dt < 4; ++dt) {
#pragma unroll
        for (int r = 0; r < 4; r += 2) {
            uint_t pk = pack2bf(acc[dt][r] * inv, acc[dt][r + 1] * inv);
            *(uint_t*)(attout + (size_t)(t0 + lr) * DMODEL + h * HSZ + dt * 16 + lg * 4 + r) = pk;
        }
    }
}

// ---------------------------------------------------------------------------
extern "C" void kernel_launch(void* const* d_in, const int* in_sizes, int n_in,
                              void* d_out, int out_size, void* d_ws, size_t ws_size,
                              hipStream_t stream) {
    const int* idx = (const int*)d_in[0];
    const float* tok_emb = (const float*)d_in[1];
    const float* pos_emb = (const float*)d_in[2];
    const float* ln1_w = (const float*)d_in[3];
    const float* ln1_b = (const float*)d_in[4];
    const float* ln2_w = (const float*)d_in[5];
    const float* ln2_b = (const float*)d_in[6];
    const float* kqv_V = (const float*)d_in[7];
    const float* kqv_z = (const float*)d_in[8];
    const float* kqv_U = (const float*)d_in[9];
    const float* proj_V = (const float*)d_in[10];
    const float* proj_z = (const float*)d_in[11];
    const float* proj_U = (const float*)d_in[12];
    const float* f1_V = (const float*)d_in[13];
    const float* f1_z = (const float*)d_in[14];
    const float* f1_U = (const float*)d_in[15];
    const float* f2_V = (const float*)d_in[16];
    const float* f2_z = (const float*)d_in[17];
    const float* f2_U = (const float*)d_in[18];
    const float* lnf_w = (const float*)d_in[19];
    const float* lnf_b = (const float*)d_in[20];
    const float* lm_w = (const float*)d_in[21];

    // ---------------- workspace layout ----------------
    char* W = (char*)d_ws;
    float* x = (float*)W;                 W += (size_t)T_SEQ * DMODEL * 4;
    __hip_bfloat16* hbuf = (__hip_bfloat16*)W; W += (size_t)T_SEQ * DMODEL * 2;
    __hip_bfloat16* t1 = (__hip_bfloat16*)W;   W += (size_t)T_SEQ * NKQV * 2;
    __hip_bfloat16* kqvb = (__hip_bfloat16*)W; W += (size_t)3 * NHEAD * T_SEQ * HSZ * 2;
    __hip_bfloat16* vtb = (__hip_bfloat16*)W;  W += (size_t)NHEAD * HSZ * T_SEQ * 2;
    __hip_bfloat16* attb = (__hip_bfloat16*)W; W += (size_t)T_SEQ * DMODEL * 2;
    __hip_bfloat16* ffb = (__hip_bfloat16*)W;  W += (size_t)T_SEQ * FFDIM * 2;
    __hip_bfloat16* wkV = (__hip_bfloat16*)W;  W += (size_t)NLAYER * NKQV * DMODEL * 2;
    __hip_bfloat16* wkU = (__hip_bfloat16*)W;  W += (size_t)NLAYER * 3 * NHEAD * HSZ * RH * 2;
    __hip_bfloat16* wpV = (__hip_bfloat16*)W;  W += (size_t)NLAYER * RP * DMODEL * 2;
    __hip_bfloat16* wpU = (__hip_bfloat16*)W;  W += (size_t)NLAYER * DMODEL * RP * 2;
    __hip_bfloat16* w1V = (__hip_bfloat16*)W;  W += (size_t)NLAYER * RF * DMODEL * 2;
    __hip_bfloat16* w1U = (__hip_bfloat16*)W;  W += (size_t)NLAYER * FFDIM * RF * 2;
    __hip_bfloat16* w2V = (__hip_bfloat16*)W;  W += (size_t)NLAYER * RF * FFDIM * 2;
    __hip_bfloat16* w2U = (__hip_bfloat16*)W;  W += (size_t)NLAYER * DMODEL * RF * 2;
    __hip_bfloat16* wlm = (__hip_bfloat16*)W;  W += (size_t)VOCAB * DMODEL * 2;

    auto cvt = [&](const float* src, __hip_bfloat16* dst, size_t n) {
        int n4 = (int)(n / 4);
        cvt_k<<<dim3((n4 + 255) / 256), dim3(256), 0, stream>>>(src, dst, n4);
    };
    cvt(kqv_V, wkV, (size_t)NLAYER * NKQV * DMODEL);
    cvt(kqv_U, wkU, (size_t)NLAYER * 3 * NHEAD * HSZ * RH);
    cvt(proj_V, wpV, (size_t)NLAYER * RP * DMODEL);
    cvt(proj_U, wpU, (size_t)NLAYER * DMODEL * RP);
    cvt(f1_V, w1V, (size_t)NLAYER * RF * DMODEL);
    cvt(f1_U, w1U, (size_t)NLAYER * FFDIM * RF);
    cvt(f2_V, w2V, (size_t)NLAYER * RF * FFDIM);
    cvt(f2_U, w2U, (size_t)NLAYER * DMODEL * RF);
    cvt(lm_w, wlm, (size_t)VOCAB * DMODEL);

    embed_k<<<dim3(T_SEQ * DMODEL / 4 / 256), dim3(256), 0, stream>>>(idx, tok_emb, pos_emb, x);

    const int M = T_SEQ;
    for (int l = 0; l < NLAYER; ++l) {
        ln_k<<<dim3(T_SEQ), dim3(256), 0, stream>>>(x, ln1_w + l * DMODEL, ln1_b + l * DMODEL, hbuf);
        gemm_t<64, 64, 0><<<dim3((M / 64) * (NKQV / 64)), dim3(256), 0, stream>>>(
            hbuf, wkV + (size_t)l * NKQV * DMODEL, kqv_z + (size_t)l * NKQV,
            t1, nullptr, M, NKQV, DMODEL);
        kqv2_k<<<dim3(3 * NHEAD * T_SEQ * HSZ / 256), dim3(256), 0, stream>>>(
            t1, wkU + (size_t)l * 3 * NHEAD * HSZ * RH, kqvb);
        {
            const __hip_bfloat16* kk = kqvb;
            const __hip_bfloat16* qq = kqvb + (size_t)NHEAD * T_SEQ * HSZ;
            const __hip_bfloat16* vv = kqvb + (size_t)2 * NHEAD * T_SEQ * HSZ;
            vtrans_k<<<dim3(T_SEQ / 64, NHEAD), dim3(256), 0, stream>>>(vv, vtb);
            attn_k<<<dim3(T_SEQ / 64, NHEAD), dim3(256), 0, stream>>>(qq, kk, vtb, attb);
        }
        gemm_t<64, 64, 0><<<dim3((M / 64) * (RP / 64)), dim3(256), 0, stream>>>(
            attb, wpV + (size_t)l * RP * DMODEL, proj_z + (size_t)l * RP,
            t1, nullptr, M, RP, DMODEL);
        gemm_t<128, 128, 2><<<dim3((M / 128) * (DMODEL / 128)), dim3(256), 0, stream>>>(
            t1, wpU + (size_t)l * DMODEL * RP, nullptr,
            nullptr, x, M, DMODEL, RP);
        ln_k<<<dim3(T_SEQ), dim3(256), 0, stream>>>(x, ln2_w + l * DMODEL, ln2_b + l * DMODEL, hbuf);
        gemm_t<64, 64, 0><<<dim3((M / 64) * (RF / 64)), dim3(256), 0, stream>>>(
            hbuf, w1V + (size_t)l * RF * DMODEL, f1_z + (size_t)l * RF,
            t1, nullptr, M, RF, DMODEL);
        gemm_t<128, 128, 1><<<dim3((M / 128) * (FFDIM / 128)), dim3(256), 0, stream>>>(
            t1, w1U + (size_t)l * FFDIM * RF, nullptr,
            ffb, nullptr, M, FFDIM, RF);
        gemm_t<64, 64, 0><<<dim3((M / 64) * (RF / 64)), dim3(256), 0, stream>>>(
            ffb, w2V + (size_t)l * RF * FFDIM, f2_z + (size_t)l * RF,
            t1, nullptr, M, RF, FFDIM);
        gemm_t<128, 128, 2><<<dim3((M / 128) * (DMODEL / 128)), dim3(256), 0, stream>>>(
            t1, w2U + (size_t)l * DMODEL * RF, nullptr,
            nullptr, x, M, DMODEL, RF);
    }
    ln_k<<<dim3(T_SEQ), dim3(256), 0, stream>>>(x, lnf_w, lnf_b, hbuf);
    gemm_t<128, 128, 3><<<dim3((M / 128) * (VOCAB / 128)), dim3(256), 0, stream>>>(
        hbuf, wlm, nullptr, nullptr, (float*)d_out, M, VOCAB, DMODEL);
}